// Round 9
// baseline (353.944 us; speedup 1.0000x reference)
//
#include <hip/hip_runtime.h>
#include <hip/hip_bf16.h>

#define NB 2
#define NT 2048
#define ND 1024
#define NHEADS 16
#define NKVH 4
#define HDIM 64
#define QKVD 1536   // (NHEADS + 2*NKVH) * HDIM

typedef __attribute__((ext_vector_type(8))) short short8;
typedef __attribute__((ext_vector_type(4))) float floatx4;

__device__ __forceinline__ unsigned short f2bf(float f) {
  union { float f; unsigned int u; } cv; cv.f = f;
  unsigned int u = cv.u;
  u += 0x7fffu + ((u >> 16) & 1u);   // round-to-nearest-even
  return (unsigned short)(u >> 16);
}
__device__ __forceinline__ float bf2f(unsigned short u) {
  union { unsigned int u; float f; } cv; cv.u = ((unsigned int)u) << 16; return cv.f;
}

// ------------------------------------------- one fused fp32->bf16 convert pass
#define N4_X   1048576   // NB*NT*ND/4
#define N4_WQ   393216   // QKVD*ND/4
#define N4_WO   262144   // ND*ND/4
__global__ __launch_bounds__(256) void cvt_all(
    const float* __restrict__ x, const float* __restrict__ wq,
    const float* __restrict__ wo,
    unsigned short* __restrict__ xb, unsigned short* __restrict__ wqb,
    unsigned short* __restrict__ wob) {
  int i = blockIdx.x * 256 + threadIdx.x;
  const float* src; unsigned short* dst; int j;
  if (i < N4_X)              { src = x;  dst = xb;  j = i; }
  else if (i < N4_X + N4_WQ) { src = wq; dst = wqb; j = i - N4_X; }
  else                       { src = wo; dst = wob; j = i - N4_X - N4_WQ; }
  float4 v = ((const float4*)src)[j];
  ushort4 o;
  o.x = f2bf(v.x); o.y = f2bf(v.y); o.z = f2bf(v.z); o.w = f2bf(v.w);
  ((ushort4*)dst)[j] = o;
}

// ====== single-wave GEMM, 64x64 tile, DIRECT-GLOBAL fragment reads ==========
// No LDS, no barriers. One global_load_dwordx4 per lane = one full 16x16x32
// fragment (16 rows x 64B, fully-consumed lines). XCD-aware m-panel swizzle.

// ---------------- QKV GEMM with fused rope/scale/pack epilogue --------------
// 1536 blocks: bid -> xcd=bid&7 owns m-panel; n = bid/64 = head slice hh.
__global__ __launch_bounds__(64) void gemm_qkv(
    const unsigned short* __restrict__ A,
    const unsigned short* __restrict__ Bm,
    const float* __restrict__ cosT, const float* __restrict__ sinT,
    const float* __restrict__ q_scale, const float* __restrict__ k_scale,
    unsigned short* __restrict__ qb, unsigned short* __restrict__ kb,
    unsigned short* __restrict__ vtb)
{
  const int bid = blockIdx.x;
  const int mt = (bid & 7) * 8 + ((bid >> 3) & 7);   // 0..63
  const int hh = bid >> 6;                            // 0..23, block-uniform
  const int m0 = mt * 64, n0 = hh * 64;
  const int K = ND;

  const int lane = threadIdx.x;
  const int quad = lane >> 4, l16 = lane & 15;
  const int lo8 = l16 & 7;

  const unsigned short* ar = A  + (size_t)(m0 + l16) * K + quad * 8;
  const unsigned short* br = Bm + (size_t)(n0 + l16) * K + quad * 8;

  floatx4 acc[4][4] = {};
#pragma unroll 2
  for (int k0 = 0; k0 < K; k0 += 32) {
    short8 af[4], bf[4];
#pragma unroll
    for (int mi = 0; mi < 4; mi++) af[mi] = *(const short8*)(ar + (size_t)(mi * 16) * K + k0);
#pragma unroll
    for (int ni = 0; ni < 4; ni++) bf[ni] = *(const short8*)(br + (size_t)(ni * 16) * K + k0);
#pragma unroll
    for (int mi = 0; mi < 4; mi++)
#pragma unroll
      for (int ni = 0; ni < 4; ni++)
        acc[mi][ni] = __builtin_amdgcn_mfma_f32_16x16x32_bf16(af[mi], bf[ni], acc[mi][ni], 0, 0, 0);
  }

  // ------------------------------- fused epilogue -------------------------
  if (hh >= NHEADS + NKVH) {
    // ---- v: write transposed bf16 to vtb[(b*NKV+kvh)*64 + d][t]
    const int kvh = hh - (NHEADS + NKVH);
#pragma unroll
    for (int mi = 0; mi < 4; mi++) {
      const int mrow = m0 + mi * 16 + quad * 4;
      const int bb = mrow >> 11, tt = mrow & (NT - 1);
#pragma unroll
      for (int ni = 0; ni < 4; ni++) {
        const int d = ni * 16 + l16;
        ushort4 w;
        w.x = f2bf(acc[mi][ni][0]); w.y = f2bf(acc[mi][ni][1]);
        w.z = f2bf(acc[mi][ni][2]); w.w = f2bf(acc[mi][ni][3]);
        *(ushort4*)(vtb + ((size_t)((bb * NKVH + kvh) * HDIM + d)) * NT + tt) = w;
      }
    }
  } else {
    // ---- q/k: rope first 16 dims (ni==0), scale, write head-major bf16
    float scl; unsigned short* dst0; int hloc, nh;
    if (hh < NHEADS) { scl = q_scale[hh] * (0.125f * 1.44269504088896f); hloc = hh; dst0 = qb; nh = NHEADS; }
    else             { scl = k_scale[hh - NHEADS]; hloc = hh - NHEADS; dst0 = kb; nh = NKVH; }
#pragma unroll
    for (int mi = 0; mi < 4; mi++) {
#pragma unroll
      for (int r = 0; r < 4; r++) {
        const int mrow = m0 + mi * 16 + quad * 4 + r;
        const int bb = mrow >> 11, tt = mrow & (NT - 1);
        unsigned short* drow = dst0 + ((size_t)((bb * nh + hloc) * NT + tt)) * HDIM;

        const float own = acc[mi][0][r];
        const float oth = __shfl_xor(own, 8);
        const float c = cosT[tt * 8 + lo8], s = sinT[tt * 8 + lo8];
        const float roped = (l16 < 8) ? (own * c - oth * s)
                                      : (oth * s + own * c);
        drow[l16] = f2bf(roped * scl);
#pragma unroll
        for (int ni = 1; ni < 4; ni++)
          drow[ni * 16 + l16] = f2bf(acc[mi][ni][r] * scl);
      }
    }
  }
}

// ------------- out GEMM: C = A * B^T (fp32 C), direct-global frags ----------
// 1024 blocks: xcd=bid&7 owns m-panel; n = bid/64 (0..15).
__global__ __launch_bounds__(64) void gemm_out(
    const unsigned short* __restrict__ A,
    const unsigned short* __restrict__ Bm,
    float* __restrict__ C, int M, int N, int K)
{
  const int bid = blockIdx.x;
  const int mt = (bid & 7) * 8 + ((bid >> 3) & 7);
  const int nt = bid >> 6;
  const int m0 = mt * 64, n0 = nt * 64;

  const int lane = threadIdx.x;
  const int quad = lane >> 4, l16 = lane & 15;

  const unsigned short* ar = A  + (size_t)(m0 + l16) * K + quad * 8;
  const unsigned short* br = Bm + (size_t)(n0 + l16) * K + quad * 8;

  floatx4 acc[4][4] = {};
#pragma unroll 2
  for (int k0 = 0; k0 < K; k0 += 32) {
    short8 af[4], bf[4];
#pragma unroll
    for (int mi = 0; mi < 4; mi++) af[mi] = *(const short8*)(ar + (size_t)(mi * 16) * K + k0);
#pragma unroll
    for (int ni = 0; ni < 4; ni++) bf[ni] = *(const short8*)(br + (size_t)(ni * 16) * K + k0);
#pragma unroll
    for (int mi = 0; mi < 4; mi++)
#pragma unroll
      for (int ni = 0; ni < 4; ni++)
        acc[mi][ni] = __builtin_amdgcn_mfma_f32_16x16x32_bf16(af[mi], bf[ni], acc[mi][ni], 0, 0, 0);
  }

#pragma unroll
  for (int mi = 0; mi < 4; mi++)
#pragma unroll
    for (int ni = 0; ni < 4; ni++)
#pragma unroll
      for (int r = 0; r < 4; r++) {
        int m = m0 + mi * 16 + quad * 4 + r;
        int n = n0 + ni * 16 + l16;
        C[(size_t)m * N + n] = acc[mi][ni][r];
      }
}

// ----------------------------- flash attention: direct-L2 K/V, ZERO barriers
// Fragments of K and V read straight from global (L2-resident; 16 rows x 64B
// fully-consumed lines per load). LDS only for the wave-private P round-trip.
// Fixed-m base-2 softmax (additive partials), uniform KV-chunking as before.
__global__ __launch_bounds__(256) void fattn(
    const unsigned short* __restrict__ qb,   // [B][NH][T][64]
    const unsigned short* __restrict__ kb,   // [B][NKV][T][64]
    const unsigned short* __restrict__ vtb,  // [B][NKV][64][T]
    unsigned short* __restrict__ aob,        // [B][T][NH*64]
    float* __restrict__ pbuf)                // slots x (64*64 O + 64 l) fp32
{
  const int idx = blockIdx.x;
  const int h = blockIdx.y, b = blockIdx.z;
  const int kv = h >> 2;

  int qt, j0, cnt, chunk; bool direct;
  if (idx < 16) { qt = 16 + idx; j0 = 0; cnt = 16; chunk = 0; direct = false; }
  else {
    int rel = idx - 16, s = 16 - (rel >> 1);
    if ((rel & 1) == 0) { qt = s - 1;  j0 = 0;  cnt = s; chunk = 0; direct = true;  }
    else                { qt = s + 15; j0 = 16; cnt = s; chunk = 1; direct = false; }
  }

  const int tid = threadIdx.x;
  const int wid = tid >> 6, lane = tid & 63;
  const int quad = lane >> 4, l16 = lane & 15;
  const int hi8 = l16 >> 3, lo8 = l16 & 7;

  __shared__ __align__(16) short Ps[4][16][64];   // [wave][q][t], chunk^(q&7)

  // ---- Q fragments (16 q-rows per wave)
  const unsigned short* qg = qb + ((size_t)((b * NHEADS + h) * NT + qt * 64)) * HDIM;
  const int qrow = wid * 16 + l16;
  short8 aq0 = *(const short8*)(qg + (size_t)qrow * HDIM + quad * 8);
  short8 aq1 = *(const short8*)(qg + (size_t)qrow * HDIM + 32 + quad * 8);

  // ---- direct-global fragment base pointers
  // K frag (nb): row jt*64 + nb*16 + l16, k-chunk quad*8 (+32)
  const unsigned short* krow = kb + ((size_t)((b * NKVH + kv) * NT) + l16) * HDIM + quad * 8;
  // V frag (nb): d-row nb*16 + l16, t-chunk jt*64 + quad*8 (+32)
  const unsigned short* vrow = vtb + ((size_t)((b * NKVH + kv) * HDIM) + l16) * NT + quad * 8;

  // P LDS offsets (XOR-swizzled, wave-private)
  const int cs0 = (quad ^ lo8) * 8;
  const int cs1 = cs0 ^ 32;
  int pwo[4][4];
#pragma unroll
  for (int r = 0; r < 4; r++) {
    const int row = quad * 4 + r;
#pragma unroll
    for (int nb = 0; nb < 4; nb++)
      pwo[r][nb] = wid * 1024 + row * 64 + (((nb * 2 + hi8) ^ (row & 7)) * 8) + lo8;
  }
  short* psf = &Ps[0][0][0];

  floatx4 acc_o[4] = {};
  float lsum[4] = {0.f, 0.f, 0.f, 0.f};

  for (int i = 0; i < cnt; i++) {
    const int jt = j0 + i;
    const unsigned short* kf = krow + (size_t)jt * 64 * HDIM;
    const unsigned short* vf = vrow + jt * 64;

    // ---- S = Q @ K^T, K-frags direct from global
    floatx4 s[4] = {};
#pragma unroll
    for (int nb = 0; nb < 4; nb++) {
      short8 bk0 = *(const short8*)(kf + (size_t)(nb * 16) * HDIM);
      short8 bk1 = *(const short8*)(kf + (size_t)(nb * 16) * HDIM + 32);
      s[nb] = __builtin_amdgcn_mfma_f32_16x16x32_bf16(aq0, bk0, s[nb], 0, 0, 0);
      s[nb] = __builtin_amdgcn_mfma_f32_16x16x32_bf16(aq1, bk1, s[nb], 0, 0, 0);
    }

    if (jt == qt) {   // causal mask, diagonal tile only
#pragma unroll
      for (int nb = 0; nb < 4; nb++) {
        int col = nb * 16 + l16;
#pragma unroll
        for (int r = 0; r < 4; r++)
          if (col > wid * 16 + quad * 4 + r) s[nb][r] = -INFINITY;
      }
    }

    // ---- p = exp2(s); per-lane l partials; write P (truncation bf16)
#pragma unroll
    for (int r = 0; r < 4; r++) {
#pragma unroll
      for (int nb = 0; nb < 4; nb++) {
        float p = __builtin_amdgcn_exp2f(s[nb][r]);
        lsum[r] += p;
        psf[pwo[r][nb]] = (short)(__float_as_uint(p) >> 16);
      }
    }

    // ---- O += P @ V, V-frags direct from global; P from wave-private LDS
    short8 ap0 = *(const short8*)&Ps[wid][l16][cs0];
    short8 ap1 = *(const short8*)&Ps[wid][l16][cs1];
#pragma unroll
    for (int nb = 0; nb < 4; nb++) {
      short8 bv0 = *(const short8*)(vf + (size_t)(nb * 16) * NT);
      short8 bv1 = *(const short8*)(vf + (size_t)(nb * 16) * NT + 32);
      acc_o[nb] = __builtin_amdgcn_mfma_f32_16x16x32_bf16(ap0, bv0, acc_o[nb], 0, 0, 0);
      acc_o[nb] = __builtin_amdgcn_mfma_f32_16x16x32_bf16(ap1, bv1, acc_o[nb], 0, 0, 0);
    }
  }

  if (direct) {
    // ---- epilogue: reduce l, normalize, v-orthogonalize (v from global)
#pragma unroll
    for (int r = 0; r < 4; r++) {
      float ls = lsum[r];
#pragma unroll
      for (int off = 1; off < 16; off <<= 1) ls += __shfl_xor(ls, off);
      const float invl = 1.f / ls;

      const int rowl = wid * 16 + quad * 4 + r;
      const unsigned short* vd_p = vtb + ((size_t)((b * NKVH + kv) * HDIM) + l16) * NT + qt * 64 + rowl;
      float vd[4], dot = 0.f, vv = 0.f;
#pragma unroll
      for (int nb = 0; nb < 4; nb++) {
        vd[nb] = bf2f(vd_p[(size_t)(nb * 16) * NT]);
        dot += acc_o[nb][r] * invl * vd[nb];
        vv  += vd[nb] * vd[nb];
      }
#pragma unroll
      for (int off = 1; off < 16; off <<= 1) {
        dot += __shfl_xor(dot, off);
        vv  += __shfl_xor(vv, off);
      }
      const float coef = dot / fmaxf(vv, 1e-8f);
      unsigned short* dst = aob + ((size_t)(b * NT + qt * 64 + rowl)) * ND + h * HDIM + l16;
#pragma unroll
      for (int nb = 0; nb < 4; nb++)
        dst[nb * 16] = f2bf(acc_o[nb][r] * invl - coef * vd[nb]);
    }
  } else {
    const int slot = ((b * NHEADS + h) * 16 + (qt - 16)) * 2 + chunk;
    float* pO = pbuf + (size_t)slot * 4160;
    float* pl = pO + 4096;
#pragma unroll
    for (int r = 0; r < 4; r++) {
      float ls = lsum[r];
#pragma unroll
      for (int off = 1; off < 16; off <<= 1) ls += __shfl_xor(ls, off);
      const int rowl = wid * 16 + quad * 4 + r;
      if (l16 == 0) pl[rowl] = ls;
#pragma unroll
      for (int nb = 0; nb < 4; nb++)
        pO[rowl * 64 + nb * 16 + l16] = acc_o[nb][r];
    }
  }
}

// --------------- reduction for qt>=16: sum 2 partials, normalize, v-orth, store
__global__ __launch_bounds__(256) void redn(
    const float* __restrict__ pbuf,
    const unsigned short* __restrict__ vtb,
    unsigned short* __restrict__ aob)
{
  const int qt = 16 + blockIdx.x;
  const int h = blockIdx.y, b = blockIdx.z;
  const int kv = h >> 2;
  const int tid = threadIdx.x;

  const int slot0 = ((b * NHEADS + h) * 16 + blockIdx.x) * 2;
  const float* O0 = pbuf + (size_t)slot0 * 4160;
  const float* O1 = O0 + 4160;
  const float* l0 = O0 + 4096;
  const float* l1 = O1 + 4096;

  __shared__ short vt[64][66];

  {
    const int d = tid >> 2, tq = (tid & 3) * 16;
    const unsigned short* src = vtb + ((size_t)((b * NKVH + kv) * HDIM + d)) * NT + qt * 64 + tq;
    short8 v0 = *(const short8*)src;
    short8 v1 = *(const short8*)(src + 8);
    *(short8*)&vt[d][tq] = v0;
    *(short8*)&vt[d][tq + 8] = v1;
  }
  __syncthreads();

  const int row = tid >> 2, dq = tid & 3;
  const float invl = 1.f / (l0[row] + l1[row]);

  float o[16], vd[16];
  float dot = 0.f, vv = 0.f;
#pragma unroll
  for (int j = 0; j < 16; j++) {
    const int d = dq * 16 + j;
    float ov = (O0[row * 64 + d] + O1[row * 64 + d]) * invl;
    float v  = bf2f((unsigned short)vt[d][row]);
    o[j] = ov; vd[j] = v;
    dot += ov * v; vv += v * v;
  }
  dot += __shfl_xor(dot, 1); dot += __shfl_xor(dot, 2);
  vv  += __shfl_xor(vv, 1);  vv  += __shfl_xor(vv, 2);
  const float coef = dot / fmaxf(vv, 1e-8f);

  unsigned short* dst = aob + ((size_t)(b * NT + qt * 64 + row)) * ND + h * HDIM + dq * 16;
  ushort4 w0, w1, w2, w3;
  w0.x = f2bf(o[0] - coef * vd[0]);  w0.y = f2bf(o[1] - coef * vd[1]);
  w0.z = f2bf(o[2] - coef * vd[2]);  w0.w = f2bf(o[3] - coef * vd[3]);
  w1.x = f2bf(o[4] - coef * vd[4]);  w1.y = f2bf(o[5] - coef * vd[5]);
  w1.z = f2bf(o[6] - coef * vd[6]);  w1.w = f2bf(o[7] - coef * vd[7]);
  w2.x = f2bf(o[8] - coef * vd[8]);  w2.y = f2bf(o[9] - coef * vd[9]);
  w2.z = f2bf(o[10] - coef * vd[10]); w2.w = f2bf(o[11] - coef * vd[11]);
  w3.x = f2bf(o[12] - coef * vd[12]); w3.y = f2bf(o[13] - coef * vd[13]);
  w3.z = f2bf(o[14] - coef * vd[14]); w3.w = f2bf(o[15] - coef * vd[15]);
  ((ushort4*)dst)[0] = w0; ((ushort4*)dst)[1] = w1;
  ((ushort4*)dst)[2] = w2; ((ushort4*)dst)[3] = w3;
}

// ---------------------------------------------------------------------- launch
extern "C" void kernel_launch(void* const* d_in, const int* in_sizes, int n_in,
                              void* d_out, int out_size, void* d_ws, size_t ws_size,
                              hipStream_t stream) {
  const float* x       = (const float*)d_in[0];
  const float* cosT    = (const float*)d_in[1];
  const float* sinT    = (const float*)d_in[2];
  const float* w_qkv   = (const float*)d_in[4];
  const float* w_out   = (const float*)d_in[5];
  const float* q_scale = (const float*)d_in[6];
  const float* k_scale = (const float*)d_in[7];
  float* out = (float*)d_out;

  // layout (bytes). pbuf (17 MB) overlays xb+wqkvb (dead after gemm_qkv).
  char* ws = (char*)d_ws;
  unsigned short* xb    = (unsigned short*)ws;                   // 0      .. 8 MB
  unsigned short* wqkvb = (unsigned short*)(ws + 8388608);       // 8 MB   .. 11 MB
  float*          pbuf  = (float*)ws;                            // 0      .. 17 MB (overlay)
  unsigned short* woutb = (unsigned short*)(ws + 17825792);      // 17 MB  .. 19 MB
  unsigned short* qb    = (unsigned short*)(ws + 19922944);      // 19 MB  .. 27 MB
  unsigned short* kb    = (unsigned short*)(ws + 28311552);      // 27 MB  .. 29 MB
  unsigned short* vtb   = (unsigned short*)(ws + 30408704);      // 29 MB  .. 31 MB
  unsigned short* aob   = (unsigned short*)(ws + 32505856);      // 31 MB  .. 39 MB

  // 1) all fp32->bf16 converts in one launch
  cvt_all<<<(N4_X + N4_WQ + N4_WO) / 256, 256, 0, stream>>>(
      x, w_qkv, w_out, xb, wqkvb, woutb);

  // 2) QKV GEMM + fused rope/scale/pack (direct-global frags, 1536 blocks)
  gemm_qkv<<<1536, 64, 0, stream>>>(
      xb, wqkvb, cosT, sinT, q_scale, k_scale, qb, kb, vtb);

  // 3) flash attention (direct-L2 K/V, zero barriers)
  fattn<<<dim3(48, NHEADS, NB), 256, 0, stream>>>(qb, kb, vtb, aob, pbuf);
  redn<<<dim3(16, NHEADS, NB), 256, 0, stream>>>(pbuf, vtb, aob);

  // 4) out = ao @ w_out^T (direct-global frags, 1024 blocks)
  gemm_out<<<1024, 64, 0, stream>>>(
      aob, woutb, out, NB * NT, ND, ND);
}